// Round 5
// baseline (12023.307 us; speedup 1.0000x reference)
//
#include <hip/hip_runtime.h>
#include <hip/hip_bf16.h>

constexpr int kB  = 16;
constexpr int kN  = 1024;
constexpr int kH  = 64;
constexpr int kNB = 64;
constexpr int kNT = 16;   // kN / kNB

__device__ __forceinline__ float lane_bcast(float v, int lane) {
  return __builtin_bit_cast(float,
      __builtin_amdgcn_readlane(__builtin_bit_cast(int, v), lane));
}

// ---------------------------------------------------------------------------
// Kernel 1: per-row MLPs (env & omega), gamma, decohered, omega staging.
// One wave (64 lanes) per (b,n) row. Lane = h index.
// ---------------------------------------------------------------------------
__global__ __launch_bounds__(64) void rows_kernel(
    const float* __restrict__ gene, const float* __restrict__ coh,
    const float* __restrict__ gbase,
    const float* __restrict__ ew1, const float* __restrict__ eb1,
    const float* __restrict__ ew2, const float* __restrict__ eb2,
    const float* __restrict__ ow1, const float* __restrict__ ob1,
    const float* __restrict__ ow2, const float* __restrict__ ob2,
    float* __restrict__ out_dec, float* __restrict__ out_gamma,
    float* __restrict__ ws_omega)
{
  int row = blockIdx.x;          // b*kN + n
  int n   = row & (kN - 1);
  int t   = threadIdx.x;         // 0..63
  float g = gene[(size_t)row * kH + t];

  float s = g;
  #pragma unroll
  for (int off = 32; off >= 1; off >>= 1) s += __shfl_xor(s, off);
  float classical = s * (1.0f / kH);

  bool isEnv = t < 32;
  int  j     = isEnv ? t : (t - 32);
  const float* w1 = isEnv ? ew1 : ow1;
  float acc = isEnv ? eb1[j] : ob1[j];
  #pragma unroll
  for (int h = 0; h < kH; ++h) {
    float gh = __shfl(g, h);
    acc = fmaf(gh, w1[h * 32 + j], acc);
  }
  float sl   = acc * (1.0f / (1.0f + expf(-acc)));   // silu
  float term = sl * (isEnv ? ew2[j] : ow2[j]);
  #pragma unroll
  for (int off = 16; off >= 1; off >>= 1) term += __shfl_xor(term, off);
  float env_sum = __shfl(term, 0);
  float om_sum  = __shfl(term, 32);

  float env   = 1.0f / (1.0f + expf(-(env_sum + eb2[0])));
  float gamma = (1.0f / (1.0f + expf(-gbase[n]))) * (1.0f + env);

  float dec = (1.0f - gamma) * coh[(size_t)row * kH + t] + gamma * classical;
  out_dec[(size_t)row * kH + t] = dec;
  if (t == 0)  out_gamma[row] = gamma;
  if (t == 63) ws_omega[row]  = om_sum + ob2[0];
}

// ---------------------------------------------------------------------------
// Kernel 2: cell mean + cosine-sim softmax -> state_probs. One block per batch.
// ---------------------------------------------------------------------------
__global__ __launch_bounds__(256) void probs_kernel(
    const float* __restrict__ gene, const float* __restrict__ emb,
    float* __restrict__ outp)
{
  __shared__ float red[256];
  __shared__ float cell[64];
  int b = blockIdx.x, t = threadIdx.x;
  int h = t & 63, seg = t >> 6;
  float s = 0.0f;
  for (int n = seg * 256; n < seg * 256 + 256; ++n)
    s += gene[((size_t)b * kN + n) * kH + h];
  red[t] = s;
  __syncthreads();
  if (t < 64) cell[t] = (red[t] + red[t + 64] + red[t + 128] + red[t + 192]) * (1.0f / kN);
  __syncthreads();
  if (t == 0) {
    float nc = 0.0f;
    for (int x = 0; x < 64; ++x) nc += cell[x] * cell[x];
    nc = fmaxf(sqrtf(nc), 1e-12f);
    float l[2];
    for (int s2 = 0; s2 < 2; ++s2) {
      float ne = 0.0f, dot = 0.0f;
      for (int x = 0; x < 64; ++x) { float e = emb[s2 * 64 + x]; ne += e * e; }
      ne = fmaxf(sqrtf(ne), 1e-12f);
      for (int x = 0; x < 64; ++x) dot += (cell[x] / nc) * (emb[s2 * 64 + x] / ne);
      l[s2] = dot * 10.0f;   // /0.1
    }
    float m  = fmaxf(l[0], l[1]);
    float e0 = expf(l[0] - m), e1 = expf(l[1] - m);
    outp[b * 2 + 0] = e0 / (e0 + e1);
    outp[b * 2 + 1] = e1 / (e0 + e1);
  }
}

// ---------------------------------------------------------------------------
// Kernel 3: omega_mean per batch.
// ---------------------------------------------------------------------------
__global__ __launch_bounds__(256) void omean_kernel(
    const float* __restrict__ om, float* __restrict__ omm)
{
  __shared__ float red[256];
  int b = blockIdx.x, t = threadIdx.x;
  float s = om[b * kN + t] + om[b * kN + t + 256] + om[b * kN + t + 512] + om[b * kN + t + 768];
  red[t] = s;
  __syncthreads();
  for (int off = 128; off >= 1; off >>= 1) {
    if (t < off) red[t] += red[t + off];
    __syncthreads();
  }
  if (t == 0) omm[b] = red[0] * (1.0f / kN);
}

// ---------------------------------------------------------------------------
// Kernel 4a: H_sym (fp32).  4b: A = w*I - H_sym (+ i*eta on diag) for a chunk.
// ---------------------------------------------------------------------------
__global__ __launch_bounds__(256) void hs_kernel(
    const float* __restrict__ Hm, float* __restrict__ Hs)
{
  int idx = blockIdx.x * 256 + threadIdx.x;
  int i = idx >> 10, j = idx & 1023;
  Hs[idx] = 0.5f * (Hm[i * kN + j] + Hm[j * kN + i]);
}

__global__ __launch_bounds__(256) void build_kernel(
    const float* __restrict__ Hs, const float* __restrict__ omm,
    float* __restrict__ Are, float* __restrict__ Aim, int b0)
{
  int bb = blockIdx.y;
  int idx = blockIdx.x * 256 + threadIdx.x;
  int i = idx >> 10, j = idx & 1023;
  float wr = omm[b0 + bb];
  Are[(size_t)bb * kN * kN + idx] = ((i == j) ? wr : 0.0f) - Hs[idx];
  Aim[(size_t)bb * kN * kN + idx] = (i == j) ? 0.01f : 0.0f;
}

// ---------------------------------------------------------------------------
// Kernel 5 (REWRITTEN): invert 64x64 complex pivot block, one WAVE per batch,
// column-per-lane fully register-resident, no LDS / no barriers. Broadcasts
// via v_readlane (indices static after full unroll). No-pivot GJ is valid:
// Im(R)=eta*I>0 keeps every Schur pivot away from 0.
// ---------------------------------------------------------------------------
__global__ __launch_bounds__(64) void pivotinv_kernel(
    const float* __restrict__ Are, const float* __restrict__ Aim,
    float* __restrict__ Pro, float* __restrict__ Pio, int kstep)
{
  int bb = blockIdx.x;
  int c  = threadIdx.x;                 // lane = column owned
  size_t base = (size_t)bb * kN * kN + (size_t)(kstep * kNB) * kN + kstep * kNB;

  float cr_[kNB], ci_[kNB];             // this lane's column (rows 0..63)
  #pragma unroll
  for (int i = 0; i < kNB; ++i) {
    cr_[i] = Are[base + (size_t)i * kN + c];
    ci_[i] = Aim[base + (size_t)i * kN + c];
  }

  #pragma unroll
  for (int s = 0; s < kNB; ++s) {
    // pivot (lane s, element s) -> all lanes
    float pr = lane_bcast(cr_[s], s);
    float pi = lane_bcast(ci_[s], s);
    float d  = 1.0f / (pr * pr + pi * pi);
    float ipr = pr * d, ipi = -pi * d;

    // scaled row-s value for this lane's column (from OLD element s)
    float vr = cr_[s], vi = ci_[s];
    float rsr = vr * ipr - vi * ipi;
    float rsi = vr * ipi + vi * ipr;

    bool mine = (c == s);
    #pragma unroll
    for (int i = 0; i < kNB; ++i) {
      if (i == s) continue;
      float fr = lane_bcast(cr_[i], s);   // OLD P[i][s] (lane s not yet updated at i)
      float fi = lane_bcast(ci_[i], s);
      // generic lanes: P[i][c] -= f_i * rs ; lane s: P[i][s] = -f_i * ipv
      float ur = cr_[i] - (fr * rsr - fi * rsi);
      float ui = ci_[i] - (fr * rsi + fi * rsr);
      float wr2 = -(fr * ipr - fi * ipi);
      float wi2 = -(fr * ipi + fi * ipr);
      cr_[i] = mine ? wr2 : ur;
      ci_[i] = mine ? wi2 : ui;
    }
    // element s: row-s scaled for c!=s, pivot inverse for c==s
    cr_[s] = mine ? ipr : rsr;
    ci_[s] = mine ? ipi : rsi;
  }

  int pbase = bb * kNB * kNB;
  #pragma unroll
  for (int i = 0; i < kNB; ++i) {
    Pro[pbase + i * kNB + c] = cr_[i];
    Pio[pbase + i * kNB + c] = ci_[i];
  }
}

// ---------------------------------------------------------------------------
// Kernel 6: column block in place: A[rt,k] <- -(A[rt,k] @ Pinv)  (rt != k).
// ---------------------------------------------------------------------------
__global__ __launch_bounds__(256) void colgemm_kernel(
    float* __restrict__ Are, float* __restrict__ Aim,
    const float* __restrict__ Pr, const float* __restrict__ Pi, int kstep)
{
  int rt = blockIdx.x;
  if (rt == kstep) return;
  int bb = blockIdx.y, t = threadIdx.x;
  __shared__ float Ar[64][33], Ai[64][33], Br[32][65], Bi[32][65];
  float cr[4][4] = {}, ci[4][4] = {};
  int r0 = (t >> 4) * 4, c0 = (t & 15) * 4;
  size_t abase = (size_t)bb * kN * kN + (size_t)(rt * kNB) * kN + kstep * kNB;
  int pbase = bb * kNB * kNB;
  for (int mc = 0; mc < 2; ++mc) {
    #pragma unroll
    for (int q = 0; q < 8; ++q) {
      int e = t * 8 + q; int r = e >> 5, c = e & 31;
      Ar[r][c] = Are[abase + (size_t)r * kN + mc * 32 + c];
      Ai[r][c] = Aim[abase + (size_t)r * kN + mc * 32 + c];
    }
    #pragma unroll
    for (int q = 0; q < 8; ++q) {
      int e = t * 8 + q; int r = e >> 6, c = e & 63;
      Br[r][c] = Pr[pbase + (mc * 32 + r) * kNB + c];
      Bi[r][c] = Pi[pbase + (mc * 32 + r) * kNB + c];
    }
    __syncthreads();
    for (int m = 0; m < 32; ++m) {
      float arv[4], aiv[4], brv[4], biv[4];
      #pragma unroll
      for (int i2 = 0; i2 < 4; ++i2) { arv[i2] = Ar[r0 + i2][m]; aiv[i2] = Ai[r0 + i2][m]; }
      #pragma unroll
      for (int j2 = 0; j2 < 4; ++j2) { brv[j2] = Br[m][c0 + j2]; biv[j2] = Bi[m][c0 + j2]; }
      #pragma unroll
      for (int i2 = 0; i2 < 4; ++i2)
        #pragma unroll
        for (int j2 = 0; j2 < 4; ++j2) {
          cr[i2][j2] += arv[i2] * brv[j2] - aiv[i2] * biv[j2];
          ci[i2][j2] += arv[i2] * biv[j2] + aiv[i2] * brv[j2];
        }
    }
    __syncthreads();
  }
  #pragma unroll
  for (int i2 = 0; i2 < 4; ++i2)
    #pragma unroll
    for (int j2 = 0; j2 < 4; ++j2) {
      Are[abase + (size_t)(r0 + i2) * kN + c0 + j2] = -cr[i2][j2];
      Aim[abase + (size_t)(r0 + i2) * kN + c0 + j2] = -ci[i2][j2];
    }
}

// ---------------------------------------------------------------------------
// Kernel 7: trailing update A[i,j] += A[i,k]_new @ A[k,j]_old  (i,j != k).
// ---------------------------------------------------------------------------
__global__ __launch_bounds__(256) void update_kernel(
    float* __restrict__ Are, float* __restrict__ Aim, int kstep)
{
  int rt = blockIdx.x, ct = blockIdx.y, bb = blockIdx.z;
  if (rt == kstep || ct == kstep) return;
  int t = threadIdx.x;
  size_t colbase = (size_t)bb * kN * kN + (size_t)(rt * kNB) * kN + kstep * kNB;
  size_t rowbase = (size_t)bb * kN * kN + (size_t)(kstep * kNB) * kN + ct * kNB;
  size_t cb      = (size_t)bb * kN * kN + (size_t)(rt * kNB) * kN + ct * kNB;
  __shared__ float Ar[64][33], Ai[64][33], Br[32][65], Bi[32][65];
  float cr[4][4] = {}, ci[4][4] = {};
  int r0 = (t >> 4) * 4, c0 = (t & 15) * 4;
  for (int mc = 0; mc < 2; ++mc) {
    #pragma unroll
    for (int q = 0; q < 8; ++q) {
      int e = t * 8 + q; int r = e >> 5, c = e & 31;
      Ar[r][c] = Are[colbase + (size_t)r * kN + mc * 32 + c];
      Ai[r][c] = Aim[colbase + (size_t)r * kN + mc * 32 + c];
    }
    #pragma unroll
    for (int q = 0; q < 8; ++q) {
      int e = t * 8 + q; int r = e >> 6, c = e & 63;
      Br[r][c] = Are[rowbase + (size_t)(mc * 32 + r) * kN + c];
      Bi[r][c] = Aim[rowbase + (size_t)(mc * 32 + r) * kN + c];
    }
    __syncthreads();
    for (int m = 0; m < 32; ++m) {
      float arv[4], aiv[4], brv[4], biv[4];
      #pragma unroll
      for (int i2 = 0; i2 < 4; ++i2) { arv[i2] = Ar[r0 + i2][m]; aiv[i2] = Ai[r0 + i2][m]; }
      #pragma unroll
      for (int j2 = 0; j2 < 4; ++j2) { brv[j2] = Br[m][c0 + j2]; biv[j2] = Bi[m][c0 + j2]; }
      #pragma unroll
      for (int i2 = 0; i2 < 4; ++i2)
        #pragma unroll
        for (int j2 = 0; j2 < 4; ++j2) {
          cr[i2][j2] += arv[i2] * brv[j2] - aiv[i2] * biv[j2];
          ci[i2][j2] += arv[i2] * biv[j2] + aiv[i2] * brv[j2];
        }
    }
    __syncthreads();
  }
  #pragma unroll
  for (int i2 = 0; i2 < 4; ++i2)
    #pragma unroll
    for (int j2 = 0; j2 < 4; ++j2) {
      size_t idx = cb + (size_t)(r0 + i2) * kN + c0 + j2;
      Are[idx] += cr[i2][j2];
      Aim[idx] += ci[i2][j2];
    }
}

// ---------------------------------------------------------------------------
// Kernel 8: row fixup A[k,j] = Pinv @ A[k,j]_old (j != k); diag block = Pinv.
// ---------------------------------------------------------------------------
__global__ __launch_bounds__(256) void rowfix_kernel(
    float* __restrict__ Are, float* __restrict__ Aim,
    const float* __restrict__ Pr, const float* __restrict__ Pi, int kstep)
{
  int ct = blockIdx.x, bb = blockIdx.y, t = threadIdx.x;
  int pbase = bb * kNB * kNB;
  size_t rb = (size_t)bb * kN * kN + (size_t)(kstep * kNB) * kN + ct * kNB;
  if (ct == kstep) {
    for (int e = t; e < kNB * kNB; e += 256) {
      int r = e >> 6, c = e & 63;
      Are[rb + (size_t)r * kN + c] = Pr[pbase + e];
      Aim[rb + (size_t)r * kN + c] = Pi[pbase + e];
    }
    return;
  }
  __shared__ float Ar[64][33], Ai[64][33], Br[32][65], Bi[32][65];
  float cr[4][4] = {}, ci[4][4] = {};
  int r0 = (t >> 4) * 4, c0 = (t & 15) * 4;
  for (int mc = 0; mc < 2; ++mc) {
    #pragma unroll
    for (int q = 0; q < 8; ++q) {
      int e = t * 8 + q; int r = e >> 5, c = e & 31;
      Ar[r][c] = Pr[pbase + r * kNB + mc * 32 + c];
      Ai[r][c] = Pi[pbase + r * kNB + mc * 32 + c];
    }
    #pragma unroll
    for (int q = 0; q < 8; ++q) {
      int e = t * 8 + q; int r = e >> 6, c = e & 63;
      Br[r][c] = Are[rb + (size_t)(mc * 32 + r) * kN + c];
      Bi[r][c] = Aim[rb + (size_t)(mc * 32 + r) * kN + c];
    }
    __syncthreads();
    for (int m = 0; m < 32; ++m) {
      float arv[4], aiv[4], brv[4], biv[4];
      #pragma unroll
      for (int i2 = 0; i2 < 4; ++i2) { arv[i2] = Ar[r0 + i2][m]; aiv[i2] = Ai[r0 + i2][m]; }
      #pragma unroll
      for (int j2 = 0; j2 < 4; ++j2) { brv[j2] = Br[m][c0 + j2]; biv[j2] = Bi[m][c0 + j2]; }
      #pragma unroll
      for (int i2 = 0; i2 < 4; ++i2)
        #pragma unroll
        for (int j2 = 0; j2 < 4; ++j2) {
          cr[i2][j2] += arv[i2] * brv[j2] - aiv[i2] * biv[j2];
          ci[i2][j2] += arv[i2] * biv[j2] + aiv[i2] * brv[j2];
        }
    }
    __syncthreads();
  }
  #pragma unroll
  for (int i2 = 0; i2 < 4; ++i2)
    #pragma unroll
    for (int j2 = 0; j2 < 4; ++j2) {
      Are[rb + (size_t)(r0 + i2) * kN + c0 + j2] = cr[i2][j2];
      Aim[rb + (size_t)(r0 + i2) * kN + c0 + j2] = ci[i2][j2];
    }
}

// ---------------------------------------------------------------------------
// Kernel 9: |inv| -> f32 output (one chunk; out already offset by b0).
// ---------------------------------------------------------------------------
__global__ __launch_bounds__(256) void abs_kernel(
    const float* __restrict__ Are, const float* __restrict__ Aim,
    float* __restrict__ outp)
{
  size_t idx = (size_t)blockIdx.x * 256 + threadIdx.x;
  float re = Are[idx], im = Aim[idx];
  outp[idx] = sqrtf(re * re + im * im);
}

// ---------------------------------------------------------------------------
extern "C" void kernel_launch(void* const* d_in, const int* in_sizes, int n_in,
                              void* d_out, int out_size, void* d_ws, size_t ws_size,
                              hipStream_t stream)
{
  const float* gene  = (const float*)d_in[0];
  const float* coh   = (const float*)d_in[1];
  const float* emb   = (const float*)d_in[2];
  const float* gbase = (const float*)d_in[3];
  const float* ew1   = (const float*)d_in[4];
  const float* eb1   = (const float*)d_in[5];
  const float* ew2   = (const float*)d_in[6];
  const float* eb2   = (const float*)d_in[7];
  const float* ow1   = (const float*)d_in[8];
  const float* ob1   = (const float*)d_in[9];
  const float* ow2   = (const float*)d_in[10];
  const float* ob2   = (const float*)d_in[11];
  const float* Hm    = (const float*)d_in[12];

  float* out       = (float*)d_out;
  float* out_probs = out;                                  // 16*2
  float* out_dec   = out + 32;                             // 16*1024*64
  float* out_gamma = out + 32 + 1048576;                   // 16*1024
  float* out_prop  = out + 32 + 1048576 + 16384;           // 16*1024*1024

  // --- workspace sizing: chunk batches to fit ws_size -----------------------
  const size_t NN      = (size_t)kN * kN;                 // 1,048,576
  const size_t perB    = 2 * NN + 2 * (size_t)kNB * kNB;  // A(re,im) + P(re,im)
  const size_t fixedF  = NN + (size_t)kB * kN + 16;       // Hs + wsom + womm
  size_t availF = ws_size / 4;
  int chunk = 1;
  if (availF > fixedF + perB) {
    size_t c = (availF - fixedF) / perB;
    chunk = (int)(c > 16 ? 16 : c);                       // cap at 16 (all batches)
    if (chunk < 1) chunk = 1;
  }

  float* Are  = (float*)d_ws;
  float* Aim  = Are + (size_t)chunk * NN;
  float* Pr   = Aim + (size_t)chunk * NN;
  float* Pi   = Pr  + (size_t)chunk * kNB * kNB;
  float* Hs   = Pi  + (size_t)chunk * kNB * kNB;
  float* wsom = Hs  + NN;
  float* womm = wsom + (size_t)kB * kN;

  rows_kernel<<<kB * kN, 64, 0, stream>>>(gene, coh, gbase, ew1, eb1, ew2, eb2,
                                          ow1, ob1, ow2, ob2,
                                          out_dec, out_gamma, wsom);
  probs_kernel<<<kB, 256, 0, stream>>>(gene, emb, out_probs);
  omean_kernel<<<kB, 256, 0, stream>>>(wsom, womm);
  hs_kernel<<<(kN * kN) / 256, 256, 0, stream>>>(Hm, Hs);

  for (int b0 = 0; b0 < kB; b0 += chunk) {
    int c = (b0 + chunk <= kB) ? chunk : (kB - b0);
    build_kernel<<<dim3((kN * kN) / 256, c), 256, 0, stream>>>(Hs, womm, Are, Aim, b0);
    for (int k = 0; k < kNT; ++k) {
      pivotinv_kernel<<<c, 64, 0, stream>>>(Are, Aim, Pr, Pi, k);
      colgemm_kernel<<<dim3(kNT, c), 256, 0, stream>>>(Are, Aim, Pr, Pi, k);
      update_kernel<<<dim3(kNT, kNT, c), 256, 0, stream>>>(Are, Aim, k);
      rowfix_kernel<<<dim3(kNT, c), 256, 0, stream>>>(Are, Aim, Pr, Pi, k);
    }
    abs_kernel<<<c * (kN * kN / 256), 256, 0, stream>>>(
        Are, Aim, out_prop + (size_t)b0 * NN);
  }
}

// Round 6
// 4773.167 us; speedup vs baseline: 2.5189x; 2.5189x over previous
//
#include <hip/hip_runtime.h>
#include <hip/hip_bf16.h>

constexpr int kB  = 16;
constexpr int kN  = 1024;
constexpr int kH  = 64;
constexpr int kNB = 64;
constexpr int kNT = 16;   // kN / kNB

// ---------------------------------------------------------------------------
// Kernel 1: per-row MLPs (env & omega), gamma, decohered, omega staging.
// ---------------------------------------------------------------------------
__global__ __launch_bounds__(64) void rows_kernel(
    const float* __restrict__ gene, const float* __restrict__ coh,
    const float* __restrict__ gbase,
    const float* __restrict__ ew1, const float* __restrict__ eb1,
    const float* __restrict__ ew2, const float* __restrict__ eb2,
    const float* __restrict__ ow1, const float* __restrict__ ob1,
    const float* __restrict__ ow2, const float* __restrict__ ob2,
    float* __restrict__ out_dec, float* __restrict__ out_gamma,
    float* __restrict__ ws_omega)
{
  int row = blockIdx.x;          // b*kN + n
  int n   = row & (kN - 1);
  int t   = threadIdx.x;         // 0..63
  float g = gene[(size_t)row * kH + t];

  float s = g;
  #pragma unroll
  for (int off = 32; off >= 1; off >>= 1) s += __shfl_xor(s, off);
  float classical = s * (1.0f / kH);

  bool isEnv = t < 32;
  int  j     = isEnv ? t : (t - 32);
  const float* w1 = isEnv ? ew1 : ow1;
  float acc = isEnv ? eb1[j] : ob1[j];
  #pragma unroll
  for (int h = 0; h < kH; ++h) {
    float gh = __shfl(g, h);
    acc = fmaf(gh, w1[h * 32 + j], acc);
  }
  float sl   = acc * (1.0f / (1.0f + expf(-acc)));   // silu
  float term = sl * (isEnv ? ew2[j] : ow2[j]);
  #pragma unroll
  for (int off = 16; off >= 1; off >>= 1) term += __shfl_xor(term, off);
  float env_sum = __shfl(term, 0);
  float om_sum  = __shfl(term, 32);

  float env   = 1.0f / (1.0f + expf(-(env_sum + eb2[0])));
  float gamma = (1.0f / (1.0f + expf(-gbase[n]))) * (1.0f + env);

  float dec = (1.0f - gamma) * coh[(size_t)row * kH + t] + gamma * classical;
  out_dec[(size_t)row * kH + t] = dec;
  if (t == 0)  out_gamma[row] = gamma;
  if (t == 63) ws_omega[row]  = om_sum + ob2[0];
}

// ---------------------------------------------------------------------------
// Kernel 2: cell mean + cosine-sim softmax -> state_probs. One block per batch.
// ---------------------------------------------------------------------------
__global__ __launch_bounds__(256) void probs_kernel(
    const float* __restrict__ gene, const float* __restrict__ emb,
    float* __restrict__ outp)
{
  __shared__ float red[256];
  __shared__ float cell[64];
  int b = blockIdx.x, t = threadIdx.x;
  int h = t & 63, seg = t >> 6;
  float s = 0.0f;
  for (int n = seg * 256; n < seg * 256 + 256; ++n)
    s += gene[((size_t)b * kN + n) * kH + h];
  red[t] = s;
  __syncthreads();
  if (t < 64) cell[t] = (red[t] + red[t + 64] + red[t + 128] + red[t + 192]) * (1.0f / kN);
  __syncthreads();
  if (t == 0) {
    float nc = 0.0f;
    for (int x = 0; x < 64; ++x) nc += cell[x] * cell[x];
    nc = fmaxf(sqrtf(nc), 1e-12f);
    float l[2];
    for (int s2 = 0; s2 < 2; ++s2) {
      float ne = 0.0f, dot = 0.0f;
      for (int x = 0; x < 64; ++x) { float e = emb[s2 * 64 + x]; ne += e * e; }
      ne = fmaxf(sqrtf(ne), 1e-12f);
      for (int x = 0; x < 64; ++x) dot += (cell[x] / nc) * (emb[s2 * 64 + x] / ne);
      l[s2] = dot * 10.0f;   // /0.1
    }
    float m  = fmaxf(l[0], l[1]);
    float e0 = expf(l[0] - m), e1 = expf(l[1] - m);
    outp[b * 2 + 0] = e0 / (e0 + e1);
    outp[b * 2 + 1] = e1 / (e0 + e1);
  }
}

// ---------------------------------------------------------------------------
// Kernel 3: omega_mean per batch.
// ---------------------------------------------------------------------------
__global__ __launch_bounds__(256) void omean_kernel(
    const float* __restrict__ om, float* __restrict__ omm)
{
  __shared__ float red[256];
  int b = blockIdx.x, t = threadIdx.x;
  float s = om[b * kN + t] + om[b * kN + t + 256] + om[b * kN + t + 512] + om[b * kN + t + 768];
  red[t] = s;
  __syncthreads();
  for (int off = 128; off >= 1; off >>= 1) {
    if (t < off) red[t] += red[t + off];
    __syncthreads();
  }
  if (t == 0) omm[b] = red[0] * (1.0f / kN);
}

// ---------------------------------------------------------------------------
// Kernel 4a: H_sym (fp32).  4b: A = w*I - H_sym (+ i*eta on diag) for a chunk.
// ---------------------------------------------------------------------------
__global__ __launch_bounds__(256) void hs_kernel(
    const float* __restrict__ Hm, float* __restrict__ Hs)
{
  int idx = blockIdx.x * 256 + threadIdx.x;
  int i = idx >> 10, j = idx & 1023;
  Hs[idx] = 0.5f * (Hm[i * kN + j] + Hm[j * kN + i]);
}

__global__ __launch_bounds__(256) void build_kernel(
    const float* __restrict__ Hs, const float* __restrict__ omm,
    float* __restrict__ Are, float* __restrict__ Aim, int b0)
{
  int bb = blockIdx.y;
  int idx = blockIdx.x * 256 + threadIdx.x;
  int i = idx >> 10, j = idx & 1023;
  float wr = omm[b0 + bb];
  Are[(size_t)bb * kN * kN + idx] = ((i == j) ? wr : 0.0f) - Hs[idx];
  Aim[(size_t)bb * kN * kN + idx] = (i == j) ? 0.01f : 0.0f;
}

// ---------------------------------------------------------------------------
// Kernel 5 (v3): 64x64 complex pivot-block inverse, one 256-thread block per
// batch. LDS-resident float2 matrix; per GJ step: phase A stages old col-s /
// row-s (parallel, no serial section), phase B updates all 4096 elements
// branchlessly. 2 barriers/step. No-pivot GJ valid: Im(R)=eta*I>0.
// ---------------------------------------------------------------------------
__global__ __launch_bounds__(256) void pivotinv_kernel(
    const float* __restrict__ Are, const float* __restrict__ Aim,
    float* __restrict__ Pro, float* __restrict__ Pio, int kstep)
{
  __shared__ float2 P[kNB][kNB + 1];
  __shared__ float2 fcol[kNB];   // old column s
  __shared__ float2 frow[kNB];   // old row s
  int bb = blockIdx.x, t = threadIdx.x;
  size_t base = (size_t)bb * kN * kN + (size_t)(kstep * kNB) * kN + kstep * kNB;

  #pragma unroll
  for (int q = 0; q < 16; ++q) {
    int e = q * 256 + t;
    int r = e >> 6, c = e & 63;
    P[r][c] = make_float2(Are[base + (size_t)r * kN + c],
                          Aim[base + (size_t)r * kN + c]);
  }
  __syncthreads();

  const int c  = t & 63;        // thread-fixed column
  const int w  = t >> 6;        // 0..3

  for (int s = 0; s < kNB; ++s) {
    // phase A: stage old column s and old row s
    if (t < 64)        fcol[t]      = P[t][s];
    else if (t < 128)  frow[t - 64] = P[s][t - 64];
    __syncthreads();

    float2 p = fcol[s];                       // old pivot P[s][s]
    float d  = 1.0f / (p.x * p.x + p.y * p.y);
    float ipr = p.x * d, ipi = -p.y * d;

    float2 row = frow[c];                     // old P[s][c]
    float rsr = row.x * ipr - row.y * ipi;    // scaled row-s value for col c
    float rsi = row.x * ipi + row.y * ipr;

    bool cs = (c == s);
    #pragma unroll
    for (int q = 0; q < 16; ++q) {
      int i = w + 4 * q;                      // row handled this q
      float2 f   = fcol[i];                   // old P[i][s]
      float2 old = P[i][c];
      // generic: old - f*rs
      float gr = old.x - (f.x * rsr - f.y * rsi);
      float gi = old.y - (f.x * rsi + f.y * rsr);
      // column-s: -f*ipv
      float cvr = -(f.x * ipr - f.y * ipi);
      float cvi = -(f.x * ipi + f.y * ipr);
      float2 res;
      if (i == s) { res.x = cs ? ipr : rsr;  res.y = cs ? ipi : rsi; }
      else        { res.x = cs ? cvr : gr;   res.y = cs ? cvi : gi;  }
      P[i][c] = res;
    }
    __syncthreads();
  }

  int pbase = bb * kNB * kNB;
  #pragma unroll
  for (int q = 0; q < 16; ++q) {
    int e = q * 256 + t;
    int r = e >> 6, cc = e & 63;
    float2 v = P[r][cc];
    Pro[pbase + e] = v.x;
    Pio[pbase + e] = v.y;
  }
}

// ---------------------------------------------------------------------------
// Kernel 6: column block in place: A[rt,k] <- -(A[rt,k] @ Pinv)  (rt != k).
// ---------------------------------------------------------------------------
__global__ __launch_bounds__(256) void colgemm_kernel(
    float* __restrict__ Are, float* __restrict__ Aim,
    const float* __restrict__ Pr, const float* __restrict__ Pi, int kstep)
{
  int rt = blockIdx.x;
  if (rt == kstep) return;
  int bb = blockIdx.y, t = threadIdx.x;
  __shared__ float Ar[64][33], Ai[64][33], Br[32][65], Bi[32][65];
  float cr[4][4] = {}, ci[4][4] = {};
  int r0 = (t >> 4) * 4, c0 = (t & 15) * 4;
  size_t abase = (size_t)bb * kN * kN + (size_t)(rt * kNB) * kN + kstep * kNB;
  int pbase = bb * kNB * kNB;
  for (int mc = 0; mc < 2; ++mc) {
    #pragma unroll
    for (int q = 0; q < 8; ++q) {
      int e = t * 8 + q; int r = e >> 5, c = e & 31;
      Ar[r][c] = Are[abase + (size_t)r * kN + mc * 32 + c];
      Ai[r][c] = Aim[abase + (size_t)r * kN + mc * 32 + c];
    }
    #pragma unroll
    for (int q = 0; q < 8; ++q) {
      int e = t * 8 + q; int r = e >> 6, c = e & 63;
      Br[r][c] = Pr[pbase + (mc * 32 + r) * kNB + c];
      Bi[r][c] = Pi[pbase + (mc * 32 + r) * kNB + c];
    }
    __syncthreads();
    for (int m = 0; m < 32; ++m) {
      float arv[4], aiv[4], brv[4], biv[4];
      #pragma unroll
      for (int i2 = 0; i2 < 4; ++i2) { arv[i2] = Ar[r0 + i2][m]; aiv[i2] = Ai[r0 + i2][m]; }
      #pragma unroll
      for (int j2 = 0; j2 < 4; ++j2) { brv[j2] = Br[m][c0 + j2]; biv[j2] = Bi[m][c0 + j2]; }
      #pragma unroll
      for (int i2 = 0; i2 < 4; ++i2)
        #pragma unroll
        for (int j2 = 0; j2 < 4; ++j2) {
          cr[i2][j2] += arv[i2] * brv[j2] - aiv[i2] * biv[j2];
          ci[i2][j2] += arv[i2] * biv[j2] + aiv[i2] * brv[j2];
        }
    }
    __syncthreads();
  }
  #pragma unroll
  for (int i2 = 0; i2 < 4; ++i2)
    #pragma unroll
    for (int j2 = 0; j2 < 4; ++j2) {
      Are[abase + (size_t)(r0 + i2) * kN + c0 + j2] = -cr[i2][j2];
      Aim[abase + (size_t)(r0 + i2) * kN + c0 + j2] = -ci[i2][j2];
    }
}

// ---------------------------------------------------------------------------
// Kernel 7: trailing update A[i,j] += A[i,k]_new @ A[k,j]_old  (i,j != k).
// ---------------------------------------------------------------------------
__global__ __launch_bounds__(256) void update_kernel(
    float* __restrict__ Are, float* __restrict__ Aim, int kstep)
{
  int rt = blockIdx.x, ct = blockIdx.y, bb = blockIdx.z;
  if (rt == kstep || ct == kstep) return;
  int t = threadIdx.x;
  size_t colbase = (size_t)bb * kN * kN + (size_t)(rt * kNB) * kN + kstep * kNB;
  size_t rowbase = (size_t)bb * kN * kN + (size_t)(kstep * kNB) * kN + ct * kNB;
  size_t cb      = (size_t)bb * kN * kN + (size_t)(rt * kNB) * kN + ct * kNB;
  __shared__ float Ar[64][33], Ai[64][33], Br[32][65], Bi[32][65];
  float cr[4][4] = {}, ci[4][4] = {};
  int r0 = (t >> 4) * 4, c0 = (t & 15) * 4;
  for (int mc = 0; mc < 2; ++mc) {
    #pragma unroll
    for (int q = 0; q < 8; ++q) {
      int e = t * 8 + q; int r = e >> 5, c = e & 31;
      Ar[r][c] = Are[colbase + (size_t)r * kN + mc * 32 + c];
      Ai[r][c] = Aim[colbase + (size_t)r * kN + mc * 32 + c];
    }
    #pragma unroll
    for (int q = 0; q < 8; ++q) {
      int e = t * 8 + q; int r = e >> 6, c = e & 63;
      Br[r][c] = Are[rowbase + (size_t)(mc * 32 + r) * kN + c];
      Bi[r][c] = Aim[rowbase + (size_t)(mc * 32 + r) * kN + c];
    }
    __syncthreads();
    for (int m = 0; m < 32; ++m) {
      float arv[4], aiv[4], brv[4], biv[4];
      #pragma unroll
      for (int i2 = 0; i2 < 4; ++i2) { arv[i2] = Ar[r0 + i2][m]; aiv[i2] = Ai[r0 + i2][m]; }
      #pragma unroll
      for (int j2 = 0; j2 < 4; ++j2) { brv[j2] = Br[m][c0 + j2]; biv[j2] = Bi[m][c0 + j2]; }
      #pragma unroll
      for (int i2 = 0; i2 < 4; ++i2)
        #pragma unroll
        for (int j2 = 0; j2 < 4; ++j2) {
          cr[i2][j2] += arv[i2] * brv[j2] - aiv[i2] * biv[j2];
          ci[i2][j2] += arv[i2] * biv[j2] + aiv[i2] * brv[j2];
        }
    }
    __syncthreads();
  }
  #pragma unroll
  for (int i2 = 0; i2 < 4; ++i2)
    #pragma unroll
    for (int j2 = 0; j2 < 4; ++j2) {
      size_t idx = cb + (size_t)(r0 + i2) * kN + c0 + j2;
      Are[idx] += cr[i2][j2];
      Aim[idx] += ci[i2][j2];
    }
}

// ---------------------------------------------------------------------------
// Kernel 8: row fixup A[k,j] = Pinv @ A[k,j]_old (j != k); diag block = Pinv.
// ---------------------------------------------------------------------------
__global__ __launch_bounds__(256) void rowfix_kernel(
    float* __restrict__ Are, float* __restrict__ Aim,
    const float* __restrict__ Pr, const float* __restrict__ Pi, int kstep)
{
  int ct = blockIdx.x, bb = blockIdx.y, t = threadIdx.x;
  int pbase = bb * kNB * kNB;
  size_t rb = (size_t)bb * kN * kN + (size_t)(kstep * kNB) * kN + ct * kNB;
  if (ct == kstep) {
    for (int e = t; e < kNB * kNB; e += 256) {
      int r = e >> 6, c = e & 63;
      Are[rb + (size_t)r * kN + c] = Pr[pbase + e];
      Aim[rb + (size_t)r * kN + c] = Pi[pbase + e];
    }
    return;
  }
  __shared__ float Ar[64][33], Ai[64][33], Br[32][65], Bi[32][65];
  float cr[4][4] = {}, ci[4][4] = {};
  int r0 = (t >> 4) * 4, c0 = (t & 15) * 4;
  for (int mc = 0; mc < 2; ++mc) {
    #pragma unroll
    for (int q = 0; q < 8; ++q) {
      int e = t * 8 + q; int r = e >> 5, c = e & 31;
      Ar[r][c] = Pr[pbase + r * kNB + mc * 32 + c];
      Ai[r][c] = Pi[pbase + r * kNB + mc * 32 + c];
    }
    #pragma unroll
    for (int q = 0; q < 8; ++q) {
      int e = t * 8 + q; int r = e >> 6, c = e & 63;
      Br[r][c] = Are[rb + (size_t)(mc * 32 + r) * kN + c];
      Bi[r][c] = Aim[rb + (size_t)(mc * 32 + r) * kN + c];
    }
    __syncthreads();
    for (int m = 0; m < 32; ++m) {
      float arv[4], aiv[4], brv[4], biv[4];
      #pragma unroll
      for (int i2 = 0; i2 < 4; ++i2) { arv[i2] = Ar[r0 + i2][m]; aiv[i2] = Ai[r0 + i2][m]; }
      #pragma unroll
      for (int j2 = 0; j2 < 4; ++j2) { brv[j2] = Br[m][c0 + j2]; biv[j2] = Bi[m][c0 + j2]; }
      #pragma unroll
      for (int i2 = 0; i2 < 4; ++i2)
        #pragma unroll
        for (int j2 = 0; j2 < 4; ++j2) {
          cr[i2][j2] += arv[i2] * brv[j2] - aiv[i2] * biv[j2];
          ci[i2][j2] += arv[i2] * biv[j2] + aiv[i2] * brv[j2];
        }
    }
    __syncthreads();
  }
  #pragma unroll
  for (int i2 = 0; i2 < 4; ++i2)
    #pragma unroll
    for (int j2 = 0; j2 < 4; ++j2) {
      Are[rb + (size_t)(r0 + i2) * kN + c0 + j2] = cr[i2][j2];
      Aim[rb + (size_t)(r0 + i2) * kN + c0 + j2] = ci[i2][j2];
    }
}

// ---------------------------------------------------------------------------
// Kernel 9: |inv| -> f32 output (one chunk; out already offset by b0).
// ---------------------------------------------------------------------------
__global__ __launch_bounds__(256) void abs_kernel(
    const float* __restrict__ Are, const float* __restrict__ Aim,
    float* __restrict__ outp)
{
  size_t idx = (size_t)blockIdx.x * 256 + threadIdx.x;
  float re = Are[idx], im = Aim[idx];
  outp[idx] = sqrtf(re * re + im * im);
}

// ---------------------------------------------------------------------------
extern "C" void kernel_launch(void* const* d_in, const int* in_sizes, int n_in,
                              void* d_out, int out_size, void* d_ws, size_t ws_size,
                              hipStream_t stream)
{
  const float* gene  = (const float*)d_in[0];
  const float* coh   = (const float*)d_in[1];
  const float* emb   = (const float*)d_in[2];
  const float* gbase = (const float*)d_in[3];
  const float* ew1   = (const float*)d_in[4];
  const float* eb1   = (const float*)d_in[5];
  const float* ew2   = (const float*)d_in[6];
  const float* eb2   = (const float*)d_in[7];
  const float* ow1   = (const float*)d_in[8];
  const float* ob1   = (const float*)d_in[9];
  const float* ow2   = (const float*)d_in[10];
  const float* ob2   = (const float*)d_in[11];
  const float* Hm    = (const float*)d_in[12];

  float* out       = (float*)d_out;
  float* out_probs = out;                                  // 16*2
  float* out_dec   = out + 32;                             // 16*1024*64
  float* out_gamma = out + 32 + 1048576;                   // 16*1024
  float* out_prop  = out + 32 + 1048576 + 16384;           // 16*1024*1024

  // --- workspace sizing: chunk batches to fit ws_size -----------------------
  const size_t NN      = (size_t)kN * kN;                 // 1,048,576
  const size_t perB    = 2 * NN + 2 * (size_t)kNB * kNB;  // A(re,im) + P(re,im)
  const size_t fixedF  = NN + (size_t)kB * kN + 16;       // Hs + wsom + womm
  size_t availF = ws_size / 4;
  int chunk = 1;
  if (availF > fixedF + perB) {
    size_t c = (availF - fixedF) / perB;
    chunk = (int)(c > 16 ? 16 : c);                       // cap at 16 (all batches)
    if (chunk < 1) chunk = 1;
  }

  float* Are  = (float*)d_ws;
  float* Aim  = Are + (size_t)chunk * NN;
  float* Pr   = Aim + (size_t)chunk * NN;
  float* Pi   = Pr  + (size_t)chunk * kNB * kNB;
  float* Hs   = Pi  + (size_t)chunk * kNB * kNB;
  float* wsom = Hs  + NN;
  float* womm = wsom + (size_t)kB * kN;

  rows_kernel<<<kB * kN, 64, 0, stream>>>(gene, coh, gbase, ew1, eb1, ew2, eb2,
                                          ow1, ob1, ow2, ob2,
                                          out_dec, out_gamma, wsom);
  probs_kernel<<<kB, 256, 0, stream>>>(gene, emb, out_probs);
  omean_kernel<<<kB, 256, 0, stream>>>(wsom, womm);
  hs_kernel<<<(kN * kN) / 256, 256, 0, stream>>>(Hm, Hs);

  for (int b0 = 0; b0 < kB; b0 += chunk) {
    int c = (b0 + chunk <= kB) ? chunk : (kB - b0);
    build_kernel<<<dim3((kN * kN) / 256, c), 256, 0, stream>>>(Hs, womm, Are, Aim, b0);
    for (int k = 0; k < kNT; ++k) {
      pivotinv_kernel<<<c, 256, 0, stream>>>(Are, Aim, Pr, Pi, k);
      colgemm_kernel<<<dim3(kNT, c), 256, 0, stream>>>(Are, Aim, Pr, Pi, k);
      update_kernel<<<dim3(kNT, kNT, c), 256, 0, stream>>>(Are, Aim, k);
      rowfix_kernel<<<dim3(kNT, c), 256, 0, stream>>>(Are, Aim, Pr, Pi, k);
    }
    abs_kernel<<<c * (kN * kN / 256), 256, 0, stream>>>(
        Are, Aim, out_prop + (size_t)b0 * NN);
  }
}